// Round 3
// baseline (266.576 us; speedup 1.0000x reference)
//
#include <hip/hip_runtime.h>
#include <hip/hip_bf16.h>

// Sequential2D: out[i] = sum_{j in [max(0,i-2), i]} X[j] @ W[i,j]^T + sum_j b[i,j]
// X (8,32768,128) f32, W (8,8,128,128) f32, b (8,8,128) f32, out (8,32768,128) f32.
// R3: one barrier per K-chunk + double-buffered LDS. Global loads for chunk c+1
// are issued AFTER barrier(c) and consumed after the MFMA phase of chunk c —
// no barrier between issue and use, so the compiler's vmcnt(0)-before-s_barrier
// drain (m97) can no longer kill the overlap. pk-bf16 cvt cuts stage-phase VALU.

#define NOUT  8
#define NIN   8
#define DD    128
#define BATCH 32768
#define BAND  2

#define BM 128
#define BN 128
#define BK 64
#define SK (BK + 8)          // padded LDS stride (bf16 elems); 144 B/row
#define BUFE (BM * SK)       // elems per matrix per buffer

typedef __attribute__((ext_vector_type(8))) short        short8;
typedef __attribute__((ext_vector_type(4))) float        floatx4;
typedef __attribute__((ext_vector_type(4))) unsigned int uint4v;

__device__ __forceinline__ unsigned short f2bf(float f) {
    unsigned int u = __float_as_uint(f);
    u += 0x7fffu + ((u >> 16) & 1u);
    return (unsigned short)(u >> 16);
}

__device__ __forceinline__ unsigned int pk2(float lo, float hi) {
#if __has_builtin(__builtin_amdgcn_cvt_pk_bf16_f32)
    typedef __attribute__((ext_vector_type(2))) __bf16 bf16x2_t;
    bf16x2_t v = __builtin_amdgcn_cvt_pk_bf16_f32(lo, hi);
    return __builtin_bit_cast(unsigned int, v);
#else
    return ((unsigned int)f2bf(hi) << 16) | (unsigned int)f2bf(lo);
#endif
}

__global__ __launch_bounds__(512, 4)
void seq2d_kernel(const float* __restrict__ X,
                  const float* __restrict__ W,
                  const float* __restrict__ Bv,
                  float* __restrict__ out) {
    const int i  = blockIdx.y;
    const int m0 = blockIdx.x * BM;

    // [buf0: A | B][buf1: A | B]
    __shared__ unsigned short sAll[4 * BUFE];
    __shared__ float sbias[DD];

    const int tid  = threadIdx.x;
    const int lane = tid & 63;
    const int wave = tid >> 6;          // 0..7
    const int wm   = (wave & 1) * 64;   // 2x4 wave grid: 64x32 tile per wave
    const int wn   = (wave >> 1) * 32;
    const int l15  = lane & 15;
    const int quad = lane >> 4;

    int jlo = i - BAND; if (jlo < 0) jlo = 0;
    const int nc = (i - jlo + 1) * 2;   // BK-chunks over total K (always even, >=2)

    if (tid < DD) {
        float s = 0.f;
        for (int j = jlo; j <= i; ++j)
            s += Bv[(i * NIN + j) * DD + tid];
        sbias[tid] = s;
    }

    floatx4 acc[4][2];
#pragma unroll
    for (int a = 0; a < 4; ++a)
#pragma unroll
        for (int c = 0; c < 2; ++c)
            acc[a][c] = (floatx4){0.f, 0.f, 0.f, 0.f};

    // staging split: 512 threads, 4 threads/row, 16 f32 each, for A and B
    const int srow = tid >> 2;          // 0..127
    const int scol = (tid & 3) << 4;    // 0,16,32,48 (elems)
    const size_t xrow_off = (size_t)(m0 + srow) * DD + scol;
    const size_t wrow_off = (size_t)srow * DD + scol;

    floatx4 pa[4], pb[4];               // one chunk's per-thread staging (32 VGPR)

    auto prefetch = [&](int c) {
        const int j  = jlo + (c >> 1);
        const int k0 = (c & 1) * BK;
        const float* __restrict__ xa = X + (size_t)j * BATCH * DD + xrow_off + k0;
#pragma unroll
        for (int t = 0; t < 4; ++t) pa[t] = *(const floatx4*)(xa + t * 4);
        const float* __restrict__ wb = W + (size_t)(i * NIN + j) * DD * DD + wrow_off + k0;
#pragma unroll
        for (int t = 0; t < 4; ++t) pb[t] = *(const floatx4*)(wb + t * 4);
    };

    auto stage = [&](int buf) {
        unsigned short* dA = sAll + buf * (2 * BUFE);
        uint4v a0 = (uint4v){pk2(pa[0][0], pa[0][1]), pk2(pa[0][2], pa[0][3]),
                             pk2(pa[1][0], pa[1][1]), pk2(pa[1][2], pa[1][3])};
        uint4v a1 = (uint4v){pk2(pa[2][0], pa[2][1]), pk2(pa[2][2], pa[2][3]),
                             pk2(pa[3][0], pa[3][1]), pk2(pa[3][2], pa[3][3])};
        uint4v b0 = (uint4v){pk2(pb[0][0], pb[0][1]), pk2(pb[0][2], pb[0][3]),
                             pk2(pb[1][0], pb[1][1]), pk2(pb[1][2], pb[1][3])};
        uint4v b1 = (uint4v){pk2(pb[2][0], pb[2][1]), pk2(pb[2][2], pb[2][3]),
                             pk2(pb[3][0], pb[3][1]), pk2(pb[3][2], pb[3][3])};
        *(uint4v*)(&dA[srow * SK + scol])            = a0;
        *(uint4v*)(&dA[srow * SK + scol + 8])        = a1;
        *(uint4v*)(&dA[BUFE + srow * SK + scol])     = b0;
        *(uint4v*)(&dA[BUFE + srow * SK + scol + 8]) = b1;
    };

    prefetch(0);
    stage(0);   // cold start: waits its own loads

    for (int c = 0; c < nc; ++c) {
        __syncthreads();                 // buf[c&1] visible; prior reads of other buf done
        const bool more = (c + 1 < nc);
        if (more) prefetch(c + 1);       // in flight across the whole MFMA phase

        const unsigned short* bA = sAll + (c & 1) * (2 * BUFE);
        const unsigned short* bB = bA + BUFE;
#pragma unroll
        for (int kk = 0; kk < BK; kk += 32) {
            short8 af[4], bfr[2];
#pragma unroll
            for (int t = 0; t < 4; ++t)
                af[t] = *(const short8*)(&bA[(wm + t * 16 + l15) * SK + kk + quad * 8]);
#pragma unroll
            for (int t = 0; t < 2; ++t)
                bfr[t] = *(const short8*)(&bB[(wn + t * 16 + l15) * SK + kk + quad * 8]);
#pragma unroll
            for (int mt = 0; mt < 4; ++mt)
#pragma unroll
                for (int nt = 0; nt < 2; ++nt)
                    acc[mt][nt] = __builtin_amdgcn_mfma_f32_16x16x32_bf16(
                        af[mt], bfr[nt], acc[mt][nt], 0, 0, 0);
        }

        if (more) stage((c + 1) & 1);    // vmcnt wait lands here, after MFMA cover
    }

    // epilogue: C/D layout row=(lane>>4)*4+r, col=lane&15 (verified R1/R2)
    float* outi = out + (size_t)i * BATCH * DD;
#pragma unroll
    for (int mt = 0; mt < 4; ++mt) {
#pragma unroll
        for (int nt = 0; nt < 2; ++nt) {
            const int n_g  = wn + nt * 16 + l15;
            const float bs = sbias[n_g];
            const int m_b  = m0 + wm + mt * 16 + quad * 4;
#pragma unroll
            for (int r = 0; r < 4; ++r)
                outi[(size_t)(m_b + r) * DD + n_g] = acc[mt][nt][r] + bs;
        }
    }
}

extern "C" void kernel_launch(void* const* d_in, const int* in_sizes, int n_in,
                              void* d_out, int out_size, void* d_ws, size_t ws_size,
                              hipStream_t stream) {
    const float* X  = (const float*)d_in[0];
    const float* W  = (const float*)d_in[1];
    const float* Bv = (const float*)d_in[2];
    float* out = (float*)d_out;

    dim3 grid(BATCH / BM, NOUT);
    seq2d_kernel<<<grid, 512, 0, stream>>>(X, W, Bv, out);
}